// Round 1
// baseline (3146.778 us; speedup 1.0000x reference)
//
#include <hip/hip_runtime.h>
#include <hip/hip_bf16.h>
#include <math.h>

#define B_    2
#define S_    2048
#define DIM_  4096
#define NH_   32
#define NKV_  8
#define HD_   128
#define NREP_ 4

typedef __attribute__((ext_vector_type(8))) short bf16x8;   // 8 bf16 in 4 VGPRs
typedef __attribute__((ext_vector_type(4))) float floatx4;  // MFMA C/D frag

__device__ __forceinline__ unsigned short f2bf(float f) {
    unsigned int u = __float_as_uint(f);
    unsigned int r = (u + 0x7FFFu + ((u >> 16) & 1u)) >> 16;  // RNE
    return (unsigned short)r;
}

// ---------------------------------------------------------------------------
// GEMM: C[M][N] = A[M][K] @ W[K][N], fp32 in/out, bf16 MFMA compute.
// 64x64 tile, BK=32, 256 threads = 4 waves; wave computes 32x32 via 2x2 MFMAs.
// LDS row stride padded to 40 (80B): b128 reads land 2-way/bank (free, m136).
// ---------------------------------------------------------------------------
#define BK  32
#define LDP 40

__global__ __launch_bounds__(256)
void gemm_f32_bf16(const float* __restrict__ A, const float* __restrict__ W,
                   float* __restrict__ C, int M, int N, int K) {
    __shared__ unsigned short As[64 * LDP];  // [m][k]
    __shared__ unsigned short Bs[64 * LDP];  // [n][k] (transposed on stage)
    const int tid  = threadIdx.x;
    const int lane = tid & 63;
    const int wave = tid >> 6;
    const int tileM = blockIdx.x * 64;
    const int tileN = blockIdx.y * 64;
    const int waveM = (wave >> 1) * 32;
    const int waveN = (wave & 1) * 32;
    const int l16  = lane & 15;
    const int quad = lane >> 4;

    floatx4 acc[2][2] = {};

    for (int k0 = 0; k0 < K; k0 += BK) {
        // stage A: 64 rows x 32 k, coalesced float4, convert to bf16
        {
            const int r = tid >> 3;         // 0..31
            const int c = (tid & 7) * 4;    // 0..28
            for (int p = 0; p < 2; ++p) {
                const int row = r + p * 32;
                const float4 v = *(const float4*)(A + (size_t)(tileM + row) * K + k0 + c);
                unsigned short* dst = &As[row * LDP + c];
                dst[0] = f2bf(v.x); dst[1] = f2bf(v.y);
                dst[2] = f2bf(v.z); dst[3] = f2bf(v.w);
            }
        }
        // stage B: W[k0..+31][tileN..+63] -> Bs[n][k] (transpose on write)
        {
            const int r = tid >> 4;         // 0..15
            const int c = (tid & 15) * 4;   // 0..60
            for (int p = 0; p < 2; ++p) {
                const int kk = r + p * 16;
                const float4 v = *(const float4*)(W + (size_t)(k0 + kk) * N + tileN + c);
                Bs[(c + 0) * LDP + kk] = f2bf(v.x);
                Bs[(c + 1) * LDP + kk] = f2bf(v.y);
                Bs[(c + 2) * LDP + kk] = f2bf(v.z);
                Bs[(c + 3) * LDP + kk] = f2bf(v.w);
            }
        }
        __syncthreads();
        for (int mi = 0; mi < 2; ++mi) {
            const bf16x8 af = *(const bf16x8*)&As[(waveM + mi * 16 + l16) * LDP + quad * 8];
            for (int ni = 0; ni < 2; ++ni) {
                const bf16x8 bf = *(const bf16x8*)&Bs[(waveN + ni * 16 + l16) * LDP + quad * 8];
                acc[mi][ni] = __builtin_amdgcn_mfma_f32_16x16x32_bf16(af, bf, acc[mi][ni], 0, 0, 0);
            }
        }
        __syncthreads();
    }
    // epilogue: C/D layout col=lane&15, row=quad*4+reg  [verified m89]
    for (int mi = 0; mi < 2; ++mi)
        for (int ni = 0; ni < 2; ++ni)
            for (int r = 0; r < 4; ++r) {
                const int row = tileM + waveM + mi * 16 + quad * 4 + r;
                const int col = tileN + waveN + ni * 16 + l16;
                C[(size_t)row * N + col] = acc[mi][ni][r];
            }
}

// ---------------------------------------------------------------------------
// RoPE + dtype conversion.
//  q: xq fp32 -> rope -> qb bf16 [b][s][h][d]
//  k: xk fp32 -> rope -> new_k fp32 (output) + kb bf16 [b][s][g][d]
//  v: xv fp32 ->          new_v fp32 (output) + vtb bf16 TRANSPOSED [b][g][d][s]
// one thread per (even,odd) pair
// ---------------------------------------------------------------------------
__global__ __launch_bounds__(256)
void rope_convert(const float* __restrict__ xq, const float* __restrict__ xk,
                  const float* __restrict__ xv, const float* __restrict__ fc,
                  unsigned short* __restrict__ qb, unsigned short* __restrict__ kb,
                  unsigned short* __restrict__ vtb,
                  float* __restrict__ new_k, float* __restrict__ new_v) {
    const long long QP = (long long)B_ * S_ * NH_ * (HD_ / 2);   // 8388608
    const long long KP = (long long)B_ * S_ * NKV_ * (HD_ / 2);  // 2097152
    const long long total = QP + 2 * KP;
    long long idx = (long long)blockIdx.x * blockDim.x + threadIdx.x;
    if (idx >= total) return;

    if (idx < QP) {                       // ---- Q: rope -> bf16
        const long long e = idx;
        const int d2 = (int)(e % (HD_ / 2));
        const long long rh = e / (HD_ / 2);       // (b*S+s)*NH + h
        const int s = (int)((rh / NH_) % S_);
        const float2 v = *(const float2*)(xq + e * 2);
        const float cs = fc[((size_t)s * (HD_ / 2) + d2) * 2 + 0];
        const float sn = fc[((size_t)s * (HD_ / 2) + d2) * 2 + 1];
        const float orr = v.x * cs - v.y * sn;
        const float oii = v.x * sn + v.y * cs;
        *(ushort2*)(qb + e * 2) = make_ushort2(f2bf(orr), f2bf(oii));
    } else if (idx < QP + KP) {           // ---- K: rope -> fp32 out + bf16
        const long long e = idx - QP;
        const int d2 = (int)(e % (HD_ / 2));
        const long long rh = e / (HD_ / 2);       // (b*S+s)*NKV + g
        const int s = (int)((rh / NKV_) % S_);
        const float2 v = *(const float2*)(xk + e * 2);
        const float cs = fc[((size_t)s * (HD_ / 2) + d2) * 2 + 0];
        const float sn = fc[((size_t)s * (HD_ / 2) + d2) * 2 + 1];
        const float orr = v.x * cs - v.y * sn;
        const float oii = v.x * sn + v.y * cs;
        *(float2*)(new_k + e * 2) = make_float2(orr, oii);
        *(ushort2*)(kb + e * 2) = make_ushort2(f2bf(orr), f2bf(oii));
    } else {                              // ---- V: passthrough fp32 + transposed bf16
        const long long e = idx - QP - KP;
        const float2 v = *(const float2*)(xv + e * 2);
        *(float2*)(new_v + e * 2) = v;
        const long long fe = e * 2;               // flat elem idx
        const int c = (int)(fe % HD_);            // even hd col
        const long long rh = fe / HD_;            // (b*S+s)*NKV + g
        const int g = (int)(rh % NKV_);
        const long long row = rh / NKV_;          // b*S + s
        const int b = (int)(row / S_);
        const int s = (int)(row % S_);
        const size_t base = ((size_t)(b * NKV_ + g) * HD_ + c) * S_ + s;
        vtb[base]      = f2bf(v.x);
        vtb[base + S_] = f2bf(v.y);
    }
}

// ---------------------------------------------------------------------------
// Flash attention (no mask, full S): 1 wave per (b, h, 16-row q-tile).
// K-tile = 32 keys: QK^T = 2 C-frags x 4 dim-chunks (8 MFMA), online softmax,
// P through LDS (C-layout -> A-layout), PV = 8 MFMA over HD chunks.
// ---------------------------------------------------------------------------
__global__ __launch_bounds__(64)
void flash_attn(const unsigned short* __restrict__ qb,
                const unsigned short* __restrict__ kb,
                const unsigned short* __restrict__ vtb,
                float* __restrict__ ctx) {
    __shared__ unsigned short Plds[16 * LDP];
    const int lane = threadIdx.x;
    const int l16  = lane & 15;
    const int quad = lane >> 4;
    const int idx = blockIdx.x;
    const int qt = idx & (S_ / 16 - 1);   // 0..127
    const int bh = idx >> 7;
    const int h = bh % NH_;
    const int b = bh / NH_;
    const int g = h / NREP_;
    const float scale = 0.08838834764831845f;  // 1/sqrt(128)

    // Q fragments: A[m=lane&15][k=quad*8+j], 4 chunks over HD=128
    bf16x8 qf[4];
    {
        const unsigned short* qp =
            qb + ((size_t)(b * S_ + qt * 16 + l16) * NH_ + h) * HD_;
        for (int c = 0; c < 4; ++c)
            qf[c] = *(const bf16x8*)(qp + c * 32 + quad * 8);
    }

    float m_i[4], l_i[4];
    for (int r = 0; r < 4; ++r) { m_i[r] = -1e30f; l_i[r] = 0.f; }
    floatx4 oacc[8] = {};

    const unsigned short* kbase = kb + ((size_t)(b * S_) * NKV_ + g) * HD_;
    const unsigned short* vbase = vtb + (size_t)(b * NKV_ + g) * HD_ * S_;

    for (int kt = 0; kt < S_; kt += 32) {
        // ---- scores: S[q][key], 16 x 32
        floatx4 sacc[2] = {};
        for (int t = 0; t < 2; ++t) {
            const unsigned short* kp = kbase + (size_t)(kt + t * 16 + l16) * NKV_ * HD_;
            for (int c = 0; c < 4; ++c) {
                const bf16x8 kf = *(const bf16x8*)(kp + c * 32 + quad * 8);
                sacc[t] = __builtin_amdgcn_mfma_f32_16x16x32_bf16(qf[c], kf, sacc[t], 0, 0, 0);
            }
        }
        // ---- online softmax: row r lives in this quad's 16 lanes
        float p0[4], p1[4], alpha[4];
        for (int r = 0; r < 4; ++r) {
            const float s0 = sacc[0][r] * scale;
            const float s1 = sacc[1][r] * scale;
            float mx = fmaxf(s0, s1);
            for (int off = 1; off < 16; off <<= 1)
                mx = fmaxf(mx, __shfl_xor(mx, off));
            const float mnew = fmaxf(m_i[r], mx);
            const float a  = __expf(m_i[r] - mnew);
            const float e0 = __expf(s0 - mnew);
            const float e1 = __expf(s1 - mnew);
            float rs = e0 + e1;
            for (int off = 1; off < 16; off <<= 1)
                rs += __shfl_xor(rs, off);
            l_i[r] = l_i[r] * a + rs;
            m_i[r] = mnew;
            p0[r] = e0; p1[r] = e1; alpha[r] = a;
        }
        for (int f = 0; f < 8; ++f)
            for (int r = 0; r < 4; ++r)
                oacc[f][r] *= alpha[r];
        // ---- P: C-layout -> LDS -> A-layout
        __syncthreads();   // protect previous iteration's Plds read
        for (int r = 0; r < 4; ++r) {
            Plds[(quad * 4 + r) * LDP + l16]      = f2bf(p0[r]);
            Plds[(quad * 4 + r) * LDP + 16 + l16] = f2bf(p1[r]);
        }
        __syncthreads();
        const bf16x8 pf = *(const bf16x8*)&Plds[l16 * LDP + quad * 8];
        // ---- PV: B[k=key][n=hd] from transposed V (contiguous keys)
        for (int f = 0; f < 8; ++f) {
            const bf16x8 vf =
                *(const bf16x8*)(vbase + (size_t)(f * 16 + l16) * S_ + kt + quad * 8);
            oacc[f] = __builtin_amdgcn_mfma_f32_16x16x32_bf16(pf, vf, oacc[f], 0, 0, 0);
        }
    }
    // ---- epilogue: ctx[b][s][h][d] fp32
    for (int r = 0; r < 4; ++r) {
        const float inv = 1.0f / l_i[r];
        const int srow = qt * 16 + quad * 4 + r;
        float* cp = ctx + ((size_t)(b * S_ + srow) * NH_ + h) * HD_ + l16;
        for (int f = 0; f < 8; ++f)
            cp[f * 16] = oacc[f][r] * inv;
    }
}

// ---------------------------------------------------------------------------
extern "C" void kernel_launch(void* const* d_in, const int* in_sizes, int n_in,
                              void* d_out, int out_size, void* d_ws, size_t ws_size,
                              hipStream_t stream) {
    const float* x  = (const float*)d_in[0];
    const float* fc = (const float*)d_in[1];
    const float* wq = (const float*)d_in[2];
    const float* wk = (const float*)d_in[3];
    const float* wv = (const float*)d_in[4];
    const float* wo = (const float*)d_in[5];

    float* out   = (float*)d_out;                       // [B,S,DIM]
    float* new_k = out + (size_t)B_ * S_ * NH_ * HD_;   // [B,S,NKV,HD]
    float* new_v = new_k + (size_t)B_ * S_ * NKV_ * HD_;

    // workspace layout (144 MB total)
    char* ws = (char*)d_ws;
    float* xq = (float*)ws;                                       // 64MB (reused as ctx)
    float* xk = (float*)(ws + (64ull  << 20));                    // 16MB
    float* xv = (float*)(ws + (80ull  << 20));                    // 16MB
    unsigned short* qb  = (unsigned short*)(ws + (96ull  << 20)); // 32MB
    unsigned short* kb  = (unsigned short*)(ws + (128ull << 20)); //  8MB
    unsigned short* vtb = (unsigned short*)(ws + (136ull << 20)); //  8MB
    float* ctx = xq;   // xq dead after rope_convert

    const int M = B_ * S_;  // 4096
    dim3 blk(256);

    gemm_f32_bf16<<<dim3(M / 64, (NH_  * HD_) / 64), blk, 0, stream>>>(x, wq, xq, M, NH_  * HD_, DIM_);
    gemm_f32_bf16<<<dim3(M / 64, (NKV_ * HD_) / 64), blk, 0, stream>>>(x, wk, xk, M, NKV_ * HD_, DIM_);
    gemm_f32_bf16<<<dim3(M / 64, (NKV_ * HD_) / 64), blk, 0, stream>>>(x, wv, xv, M, NKV_ * HD_, DIM_);

    const long long totalPairs =
        (long long)B_ * S_ * NH_ * (HD_ / 2) + 2LL * B_ * S_ * NKV_ * (HD_ / 2);
    const int ropeBlocks = (int)((totalPairs + 255) / 256);
    rope_convert<<<ropeBlocks, blk, 0, stream>>>(xq, xk, xv, fc, qb, kb, vtb, new_k, new_v);

    flash_attn<<<B_ * NH_ * (S_ / 16), 64, 0, stream>>>(qb, kb, vtb, ctx);

    gemm_f32_bf16<<<dim3(M / 64, DIM_ / 64), blk, 0, stream>>>(ctx, wo, out, M, DIM_, DIM_);
}

// Round 3
// 1883.081 us; speedup vs baseline: 1.6711x; 1.6711x over previous
//
#include <hip/hip_runtime.h>
#include <hip/hip_bf16.h>
#include <math.h>

#define B_    2
#define S_    2048
#define DIM_  4096
#define NH_   32
#define NKV_  8
#define HD_   128
#define NREP_ 4

typedef __attribute__((ext_vector_type(8))) short bf16x8;   // 8 bf16 in 4 VGPRs
typedef __attribute__((ext_vector_type(4))) float floatx4;  // MFMA C/D frag

__device__ __forceinline__ unsigned short f2bf(float f) {
    unsigned int u = __float_as_uint(f);
    unsigned int r = (u + 0x7FFFu + ((u >> 16) & 1u)) >> 16;  // RNE
    return (unsigned short)r;
}
__device__ __forceinline__ float bf2f(unsigned short u) {
    return __uint_as_float((unsigned int)u << 16);
}
// async global->LDS, 16B per lane; LDS dst = readfirstlane(base) + lane*16
__device__ __forceinline__ void gload_lds16(const unsigned short* g, unsigned short* l) {
    __builtin_amdgcn_global_load_lds(
        (const __attribute__((address_space(1))) void*)g,
        (__attribute__((address_space(3))) void*)l, 16, 0, 0);
}

// ---------------------------------------------------------------------------
// fp32 -> bf16 elementwise (same layout), n % 4 == 0
// ---------------------------------------------------------------------------
__global__ __launch_bounds__(256)
void convert_bf16(const float* __restrict__ in, unsigned short* __restrict__ out,
                  long long n) {
    long long i = ((long long)blockIdx.x * 256 + threadIdx.x) * 4;
    if (i >= n) return;
    const float4 v = *(const float4*)(in + i);
    ushort4 o;
    o.x = f2bf(v.x); o.y = f2bf(v.y); o.z = f2bf(v.z); o.w = f2bf(v.w);
    *(ushort4*)(out + i) = o;
}

// ---------------------------------------------------------------------------
// W fp32 [K][N] -> Wt bf16 [N][K]  (tiled 32x32 transpose, 256 threads)
// ---------------------------------------------------------------------------
__global__ __launch_bounds__(256)
void transpose_conv(const float* __restrict__ W, unsigned short* __restrict__ Wt,
                    int K, int N) {
    __shared__ unsigned short t[32][33];
    const int tx = threadIdx.x & 31, ty = threadIdx.x >> 5;  // ty 0..7
    const int n0 = blockIdx.x * 32, k0 = blockIdx.y * 32;
    for (int i = 0; i < 4; ++i)
        t[ty + i * 8][tx] = f2bf(W[(size_t)(k0 + ty + i * 8) * N + n0 + tx]);
    __syncthreads();
    for (int i = 0; i < 4; ++i)
        Wt[(size_t)(n0 + ty + i * 8) * K + k0 + tx] = t[tx][ty + i * 8];
}

// ---------------------------------------------------------------------------
// GEMM (m97 structure): C[M][N] = A[M][K] @ Bt[N][K]^T, bf16 in, fp32 acc.
// 128x128 tile, BK=32, 256 threads (4 waves, 64x64 each, 4x4 frags).
// Staging via global_load_lds width=16 into UNPADDED LDS (HW layout rule).
// ---------------------------------------------------------------------------
template<bool OUT_BF16>
__global__ __launch_bounds__(256)
void gemm_bt(const unsigned short* __restrict__ A,   // [M][K] bf16
             const unsigned short* __restrict__ Bt,  // [N][K] bf16
             void* __restrict__ C, int M, int N, int K) {
    __shared__ unsigned short As[128 * 32];
    __shared__ unsigned short Bs[128 * 32];
    const int tid  = threadIdx.x;
    const int lane = tid & 63;
    const int wave = tid >> 6;
    const int l16  = lane & 15;
    const int quad = lane >> 4;
    const int tileM = blockIdx.x * 128, tileN = blockIdx.y * 128;
    const int waveM = (wave >> 1) * 64, waveN = (wave & 1) * 64;

    floatx4 acc[4][4] = {};

    // staging geometry: idx = p*256+tid; 16B/lane; row = idx/4 (32 elems/row)
    const int r0 = tid >> 2, ko = (tid & 3) * 8;

    for (int k0 = 0; k0 < K; k0 += 32) {
        for (int p = 0; p < 2; ++p) {
            const int idx = p * 256 + tid;
            const int row = r0 + p * 64;
            gload_lds16(A  + (size_t)(tileM + row) * K + k0 + ko, &As[idx * 8]);
            gload_lds16(Bt + (size_t)(tileN + row) * K + k0 + ko, &Bs[idx * 8]);
        }
        __syncthreads();
        bf16x8 af[4], bfr[4];
        for (int i = 0; i < 4; ++i) {
            af[i]  = *(const bf16x8*)&As[(waveM + i * 16 + l16) * 32 + quad * 8];
            bfr[i] = *(const bf16x8*)&Bs[(waveN + i * 16 + l16) * 32 + quad * 8];
        }
        for (int mi = 0; mi < 4; ++mi)
            for (int ni = 0; ni < 4; ++ni)
                acc[mi][ni] = __builtin_amdgcn_mfma_f32_16x16x32_bf16(
                    af[mi], bfr[ni], acc[mi][ni], 0, 0, 0);
        __syncthreads();
    }
    // epilogue: C/D layout col=lane&15, row=quad*4+reg
    for (int mi = 0; mi < 4; ++mi)
        for (int r = 0; r < 4; ++r) {
            const int row = tileM + waveM + mi * 16 + quad * 4 + r;
            for (int ni = 0; ni < 4; ++ni) {
                const int col = tileN + waveN + ni * 16 + l16;
                if (OUT_BF16)
                    ((unsigned short*)C)[(size_t)row * N + col] = f2bf(acc[mi][ni][r]);
                else
                    ((float*)C)[(size_t)row * N + col] = acc[mi][ni][r];
            }
        }
}

// ---------------------------------------------------------------------------
// RoPE:
//  Q: in-place on bf16 [b][s][h][d]
//  K: xk fp32 [b][s][g][d] -> new_k fp32 (output) + kb bf16 [b][g][s][d]
//  V: new_v fp32 (already final output) -> vtb bf16 transposed [b][g][d][s]
// ---------------------------------------------------------------------------
__global__ __launch_bounds__(256)
void rope2(unsigned short* __restrict__ qio, const float* __restrict__ xk,
           const float* __restrict__ nv, const float* __restrict__ fc,
           unsigned short* __restrict__ kb, unsigned short* __restrict__ vtb,
           float* __restrict__ new_k) {
    const long long QP = (long long)B_ * S_ * NH_ * (HD_ / 2);   // 8388608
    const long long KP = (long long)B_ * S_ * NKV_ * (HD_ / 2);  // 2097152
    const long long idx = (long long)blockIdx.x * 256 + threadIdx.x;
    if (idx < QP) {
        const int d2 = (int)(idx & 63);
        const long long rh = idx >> 6;                 // (b*S+s)*NH + h
        const int s = (int)((rh / NH_) % S_);
        const ushort2 u = *(const ushort2*)(qio + idx * 2);
        const float xr = bf2f(u.x), xi = bf2f(u.y);
        const float cs = fc[((size_t)s * 64 + d2) * 2];
        const float sn = fc[((size_t)s * 64 + d2) * 2 + 1];
        *(ushort2*)(qio + idx * 2) =
            make_ushort2(f2bf(xr * cs - xi * sn), f2bf(xr * sn + xi * cs));
    } else if (idx < QP + KP) {
        const long long e = idx - QP;
        const int d2 = (int)(e & 63);
        const long long rh = e >> 6;                   // (b*S+s)*NKV + g
        const int g = (int)(rh & (NKV_ - 1));
        const long long row = rh >> 3;                 // b*S + s
        const int b = (int)(row / S_), s = (int)(row % S_);
        const float2 v = *(const float2*)(xk + e * 2);
        const float cs = fc[((size_t)s * 64 + d2) * 2];
        const float sn = fc[((size_t)s * 64 + d2) * 2 + 1];
        const float orr = v.x * cs - v.y * sn;
        const float oii = v.x * sn + v.y * cs;
        *(float2*)(new_k + e * 2) = make_float2(orr, oii);
        const size_t kbi = ((size_t)(b * NKV_ + g) * S_ + s) * HD_ + d2 * 2;
        *(ushort2*)(kb + kbi) = make_ushort2(f2bf(orr), f2bf(oii));
    } else if (idx < QP + 2 * KP) {
        const long long e = idx - QP - KP;
        const float2 v = *(const float2*)(nv + e * 2);
        const long long fe = e * 2;
        const int c = (int)(fe & (HD_ - 1));
        const long long rh = fe >> 7;                  // (b*S+s)*NKV + g
        const int g = (int)(rh & (NKV_ - 1));
        const long long row = rh >> 3;
        const int b = (int)(row / S_), s = (int)(row % S_);
        const size_t base = ((size_t)(b * NKV_ + g) * HD_ + c) * S_ + s;
        vtb[base]      = f2bf(v.x);
        vtb[base + S_] = f2bf(v.y);
    }
}

// ---------------------------------------------------------------------------
// Flash attention v2: 256 threads = 4 waves, each wave one 16-row q-tile of
// the SAME (b,h) (shared K/V in cache). K-tile = 64 keys. NO barriers: P
// round-trips through a per-wave LDS region (intra-wave DS ordering +
// explicit lgkmcnt(0)). ctx written as bf16.
// ---------------------------------------------------------------------------
__global__ __launch_bounds__(256)
void flash_attn(const unsigned short* __restrict__ qb,
                const unsigned short* __restrict__ kb,
                const unsigned short* __restrict__ vtb,
                unsigned short* __restrict__ ctxb) {
    __shared__ unsigned short Plds[4][16 * 72];
    const int tid  = threadIdx.x;
    const int wave = tid >> 6, lane = tid & 63;
    const int l16  = lane & 15, quad = lane >> 4;
    const int bi  = blockIdx.x;
    const int qt4 = bi & (S_ / 64 - 1);     // 0..31
    const int bh  = bi >> 5;
    const int h = bh & (NH_ - 1), b = bh >> 5;
    const int g = h >> 2;                   // NREP_=4
    const int qt = qt4 * 4 + wave;
    const float scale = 0.08838834764831845f;  // 1/sqrt(128)

    bf16x8 qf[4];
    {
        const unsigned short* qp =
            qb + ((size_t)(b * S_ + qt * 16 + l16) * NH_ + h) * HD_;
        for (int c = 0; c < 4; ++c) qf[c] = *(const bf16x8*)(qp + c * 32 + quad * 8);
    }

    float m_i[4], l_i[4];
    for (int r = 0; r < 4; ++r) { m_i[r] = -1e30f; l_i[r] = 0.f; }
    floatx4 oacc[8] = {};

    const unsigned short* kbase = kb  + (size_t)(b * NKV_ + g) * S_ * HD_;
    const unsigned short* vbase = vtb + (size_t)(b * NKV_ + g) * HD_ * S_;
    unsigned short* pw = &Plds[wave][0];

    for (int kt = 0; kt < S_; kt += 64) {
        // ---- scores: 16 q-rows x 64 keys (4 indep MFMA chains)
        floatx4 sacc[4] = {};
        for (int t = 0; t < 4; ++t) {
            const unsigned short* kp = kbase + (size_t)(kt + t * 16 + l16) * HD_;
            for (int c = 0; c < 4; ++c) {
                const bf16x8 kf = *(const bf16x8*)(kp + c * 32 + quad * 8);
                sacc[t] = __builtin_amdgcn_mfma_f32_16x16x32_bf16(qf[c], kf, sacc[t], 0, 0, 0);
            }
        }
        // ---- online softmax; write P (bf16) to per-wave LDS as we go
        float alpha[4];
        for (int r = 0; r < 4; ++r) {
            const float s0 = sacc[0][r] * scale, s1 = sacc[1][r] * scale;
            const float s2 = sacc[2][r] * scale, s3 = sacc[3][r] * scale;
            float mx = fmaxf(fmaxf(s0, s1), fmaxf(s2, s3));
            for (int off = 1; off < 16; off <<= 1) mx = fmaxf(mx, __shfl_xor(mx, off));
            const float mnew = fmaxf(m_i[r], mx);
            const float a  = __expf(m_i[r] - mnew);
            const float e0 = __expf(s0 - mnew), e1 = __expf(s1 - mnew);
            const float e2 = __expf(s2 - mnew), e3 = __expf(s3 - mnew);
            float rs = (e0 + e1) + (e2 + e3);
            for (int off = 1; off < 16; off <<= 1) rs += __shfl_xor(rs, off);
            l_i[r] = l_i[r] * a + rs;
            m_i[r] = mnew;
            alpha[r] = a;
            const int ro = (quad * 4 + r) * 72 + l16;
            pw[ro]      = f2bf(e0);
            pw[ro + 16] = f2bf(e1);
            pw[ro + 32] = f2bf(e2);
            pw[ro + 48] = f2bf(e3);
        }
        for (int f = 0; f < 8; ++f)
            for (int r = 0; r < 4; ++r) oacc[f][r] *= alpha[r];
        // drain our DS writes (per-wave region; no cross-wave sharing)
        asm volatile("s_waitcnt lgkmcnt(0)" ::: "memory");
        // ---- PV: P A-frags (2 k-chunks) x 8 HD frags
        for (int t2 = 0; t2 < 2; ++t2) {
            const bf16x8 pf = *(const bf16x8*)&pw[l16 * 72 + t2 * 32 + quad * 8];
            for (int f = 0; f < 8; ++f) {
                const bf16x8 vf = *(const bf16x8*)
                    (vbase + (size_t)(f * 16 + l16) * S_ + kt + t2 * 32 + quad * 8);
                oacc[f] = __builtin_amdgcn_mfma_f32_16x16x32_bf16(pf, vf, oacc[f], 0, 0, 0);
            }
        }
    }
    // ---- epilogue: ctx bf16 [b][s][h][d]
    for (int r = 0; r < 4; ++r) {
        const float inv = 1.0f / l_i[r];
        const int srow = qt * 16 + quad * 4 + r;
        unsigned short* cp = ctxb + ((size_t)(b * S_ + srow) * NH_ + h) * HD_ + l16;
        for (int f = 0; f < 8; ++f) cp[f * 16] = f2bf(oacc[f][r] * inv);
    }
}

// ---------------------------------------------------------------------------
extern "C" void kernel_launch(void* const* d_in, const int* in_sizes, int n_in,
                              void* d_out, int out_size, void* d_ws, size_t ws_size,
                              hipStream_t stream) {
    const float* x  = (const float*)d_in[0];
    const float* fc = (const float*)d_in[1];
    const float* wq = (const float*)d_in[2];
    const float* wk = (const float*)d_in[3];
    const float* wv = (const float*)d_in[4];
    const float* wo = (const float*)d_in[5];

    float* out   = (float*)d_out;                         // [B,S,DIM]
    float* new_k = out + (size_t)B_ * S_ * NH_ * HD_;     // [B,S,NKV,HD]
    float* new_v = new_k + (size_t)B_ * S_ * NKV_ * HD_;  // [B,S,NKV,HD]

    // workspace layout (144 MB total) -- R2 bug was xqb sized 16MB (needs 32MB)
    char* ws = (char*)d_ws;
    unsigned short* xb   = (unsigned short*)(ws);                  // 32MB (later ctxb)
    unsigned short* wqT  = (unsigned short*)(ws + (32ull  << 20)); // 32MB (later woT)
    unsigned short* wkT  = (unsigned short*)(ws + (64ull  << 20)); //  8MB
    unsigned short* wvT  = (unsigned short*)(ws + (72ull  << 20)); //  8MB
    unsigned short* xqb  = (unsigned short*)(ws + (80ull  << 20)); // 32MB (rope in-place)
    float*          xk   = (float*)         (ws + (112ull << 20)); // 16MB
    unsigned short* kbuf = (unsigned short*)(ws + (128ull << 20)); //  8MB
    unsigned short* vtb  = (unsigned short*)(ws + (136ull << 20)); //  8MB  (end 144MB)
    unsigned short* ctxb = xb;   // xb dead after QKV GEMMs
    unsigned short* woT  = wqT;  // wqT dead after Q GEMM

    const int M = B_ * S_;  // 4096
    dim3 blk(256);

    // ---- pre-convert activations + weights to bf16 (weights transposed [N][K])
    convert_bf16<<<(int)(((size_t)M * DIM_ / 4 + 255) / 256), blk, 0, stream>>>(
        x, xb, (long long)M * DIM_);
    transpose_conv<<<dim3(DIM_ / 32, DIM_ / 32), blk, 0, stream>>>(wq, wqT, DIM_, DIM_);
    transpose_conv<<<dim3((NKV_ * HD_) / 32, DIM_ / 32), blk, 0, stream>>>(wk, wkT, DIM_, NKV_ * HD_);
    transpose_conv<<<dim3((NKV_ * HD_) / 32, DIM_ / 32), blk, 0, stream>>>(wv, wvT, DIM_, NKV_ * HD_);

    // ---- QKV projections
    gemm_bt<true ><<<dim3(M / 128, (NH_  * HD_) / 128), blk, 0, stream>>>(xb, wqT, xqb,   M, NH_  * HD_, DIM_);
    gemm_bt<false><<<dim3(M / 128, (NKV_ * HD_) / 128), blk, 0, stream>>>(xb, wkT, xk,    M, NKV_ * HD_, DIM_);
    gemm_bt<false><<<dim3(M / 128, (NKV_ * HD_) / 128), blk, 0, stream>>>(xb, wvT, new_v, M, NKV_ * HD_, DIM_);

    // wo transpose after Q-GEMM (reuses wqT region; stream-ordered)
    transpose_conv<<<dim3(DIM_ / 32, DIM_ / 32), blk, 0, stream>>>(wo, woT, DIM_, DIM_);

    // ---- RoPE + layout conversion
    const long long totalPairs = (long long)B_ * S_ * (HD_ / 2) * (NH_ + 2 * NKV_);
    rope2<<<(int)((totalPairs + 255) / 256), blk, 0, stream>>>(
        xqb, xk, new_v, fc, kbuf, vtb, new_k);

    // ---- attention
    flash_attn<<<B_ * NH_ * (S_ / 64), blk, 0, stream>>>(xqb, kbuf, vtb, ctxb);

    // ---- output projection
    gemm_bt<false><<<dim3(M / 128, DIM_ / 128), blk, 0, stream>>>(ctxb, woT, out, M, DIM_, DIM_);
}